// Round 1
// baseline (1142.129 us; speedup 1.0000x reference)
//
#include <hip/hip_runtime.h>
#include <math.h>

#define NB 8
#define NN 2048
#define ND 256

static constexpr float EPS = 1e-6f;

// ---------------- Kernel A: per-batch sigma -> scale = 1/(D*(2h^2+eps)) ----
__global__ __launch_bounds__(256) void k_stats(const float* __restrict__ x,
                                               float* __restrict__ scale) {
    int b = blockIdx.x;
    int d = threadIdx.x;                    // 0..255 = feature
    const float* xb = x + (size_t)b * NN * ND;
    float s = 0.f, ss = 0.f;
    for (int n = 0; n < NN; ++n) {
        float v = xb[(size_t)n * ND + d];   // coalesced across threads
        s += v;
        ss += v * v;
    }
    float mean = s * (1.0f / NN);
    float var = ss * (1.0f / NN) - mean * mean;
    float sd = sqrtf(fmaxf(var, 0.f));
    __shared__ float red[256];
    red[d] = sd;
    __syncthreads();
    for (int off = 128; off > 0; off >>= 1) {
        if (d < off) red[d] += red[d + off];
        __syncthreads();
    }
    if (d == 0) {
        float sigma = red[0] * (1.0f / ND) + EPS;
        float c = powf(4.0f / (ND + 2), 1.0f / (ND + 4)) *
                  powf((float)NN, -1.0f / (ND + 4));
        float h = c * sigma + EPS;
        scale[b] = 1.0f / ((float)ND * (2.0f * h * h + EPS));
    }
}

// ---------------- Kernel B: sq[b*NN+n] = ||xf[b,n,:]||^2 -------------------
__global__ __launch_bounds__(256) void k_sq(const float* __restrict__ x,
                                            float* __restrict__ sq) {
    int row = blockIdx.x * 4 + (threadIdx.x >> 6);  // one wave per row
    int lane = threadIdx.x & 63;
    const float4* xr = (const float4*)(x + (size_t)row * ND);
    float4 v = xr[lane];                            // 64 lanes * 4 = 256
    float s = v.x * v.x + v.y * v.y + v.z * v.z + v.w * v.w;
    #pragma unroll
    for (int off = 32; off > 0; off >>= 1) s += __shfl_down(s, off, 64);
    if (lane == 0) sq[row] = s;
}

// ---------------- Kernel C: densities (fused dot + exp + row-sum) ----------
// Block = 256 threads = 16x16 thread grid, each thread owns a 4x4 dot tile.
// Block handles 64 n-rows of one batch, loops over all 2048 m in tiles of 64.
__global__ __launch_bounds__(256) void k_dens(const float* __restrict__ x,
                                              const float* __restrict__ sq,
                                              const float* __restrict__ scale,
                                              float* __restrict__ dens_out) {
    int b = blockIdx.y;
    int n0 = blockIdx.x * 64;
    const float* xb = x + (size_t)b * NN * ND;
    const float* sqb = sq + b * NN;
    float sc = scale[b];

    int tid = threadIdx.x;
    int tr = tid >> 4;   // 0..15 -> n rows tr*4 .. tr*4+3
    int tc = tid & 15;   // 0..15 -> m cols tc*4 .. tc*4+3

    // pad to 68 floats: row stride 272B (16B-aligned for float4 LDS reads),
    // bank stride 68%32=4 -> B-reads are 2-way (free per m136), A-reads broadcast
    __shared__ float As[64][68];
    __shared__ float Bs[64][68];

    float dens[4] = {0.f, 0.f, 0.f, 0.f};
    float sqn[4];
    #pragma unroll
    for (int i = 0; i < 4; ++i) sqn[i] = sqb[n0 + tr * 4 + i];

    for (int mt = 0; mt < NN / 64; ++mt) {
        int m0 = mt * 64;
        float acc[4][4];
        #pragma unroll
        for (int i = 0; i < 4; ++i)
            #pragma unroll
            for (int j = 0; j < 4; ++j) acc[i][j] = 0.f;

        for (int kk = 0; kk < ND / 64; ++kk) {
            int k0 = kk * 64;
            // cooperative load of 64x64 A and B sub-tiles (float4, coalesced)
            #pragma unroll
            for (int t = 0; t < 4; ++t) {
                int eg = tid + t * 256;        // 0..1023
                int r = eg >> 4;               // 0..63
                int c4 = (eg & 15) << 2;       // 0,4,..,60
                *(float4*)(&As[r][c4]) =
                    *(const float4*)(&xb[(size_t)(n0 + r) * ND + k0 + c4]);
                *(float4*)(&Bs[r][c4]) =
                    *(const float4*)(&xb[(size_t)(m0 + r) * ND + k0 + c4]);
            }
            __syncthreads();
            #pragma unroll
            for (int k4 = 0; k4 < 16; ++k4) {
                float4 a[4], bb[4];
                #pragma unroll
                for (int i = 0; i < 4; ++i)
                    a[i] = *(const float4*)(&As[tr * 4 + i][k4 * 4]);
                #pragma unroll
                for (int j = 0; j < 4; ++j)
                    bb[j] = *(const float4*)(&Bs[tc * 4 + j][k4 * 4]);
                #pragma unroll
                for (int i = 0; i < 4; ++i)
                    #pragma unroll
                    for (int j = 0; j < 4; ++j)
                        acc[i][j] += a[i].x * bb[j].x + a[i].y * bb[j].y +
                                     a[i].z * bb[j].z + a[i].w * bb[j].w;
            }
            __syncthreads();
        }
        // epilogue for this m-tile: exp + accumulate density
        #pragma unroll
        for (int j = 0; j < 4; ++j) {
            float sqm = sqb[m0 + tc * 4 + j];
            #pragma unroll
            for (int i = 0; i < 4; ++i) {
                float arg = -(sqn[i] + sqm - 2.0f * acc[i][j]) * sc;
                dens[i] += __expf(arg);
            }
        }
    }
    // reduce the 4 density partials across the 16 tc-lanes (consecutive lanes
    // within one wave), lane tc==0 writes
    #pragma unroll
    for (int i = 0; i < 4; ++i) {
        float v = dens[i];
        v += __shfl_xor(v, 1, 64);
        v += __shfl_xor(v, 2, 64);
        v += __shfl_xor(v, 4, 64);
        v += __shfl_xor(v, 8, 64);
        if (tc == 0) dens_out[b * NN + n0 + tr * 4 + i] = v;
    }
}

// ---------------- Kernel D: per-batch density mean/std(ddof=1) -> thr ------
__global__ __launch_bounds__(256) void k_dstats(const float* __restrict__ dens,
                                                float* __restrict__ thr) {
    int b = blockIdx.x;
    int t = threadIdx.x;
    const float* db = dens + b * NN;
    __shared__ float red[256];
    float s = 0.f;
    for (int n = t; n < NN; n += 256) s += db[n];
    red[t] = s;
    __syncthreads();
    for (int off = 128; off > 0; off >>= 1) {
        if (t < off) red[t] += red[t + off];
        __syncthreads();
    }
    float mean = red[0] * (1.0f / NN);
    __syncthreads();
    float vs = 0.f;
    for (int n = t; n < NN; n += 256) {
        float d2 = db[n] - mean;
        vs += d2 * d2;
    }
    red[t] = vs;
    __syncthreads();
    for (int off = 128; off > 0; off >>= 1) {
        if (t < off) red[t] += red[t + off];
        __syncthreads();
    }
    if (t == 0) {
        float stdv = sqrtf(red[0] / (float)(NN - 1));
        thr[b] = mean - 2.0f * stdv;
    }
}

// ---------------- Kernel E: masked feature means ---------------------------
__global__ __launch_bounds__(256) void k_mask(const float* __restrict__ x,
                                              const float* __restrict__ dens,
                                              const float* __restrict__ thr,
                                              float* __restrict__ out) {
    int b = blockIdx.x;
    int d = threadIdx.x;        // feature
    const float* xb = x + (size_t)b * NN * ND;
    const float* db = dens + b * NN;
    float tv = thr[b];
    float s = 0.f;
    int cnt = 0;
    for (int n = 0; n < NN; ++n) {
        if (db[n] > tv) {       // uniform across block -> no divergence
            s += xb[(size_t)n * ND + d];
            ++cnt;
        }
    }
    float denom = (float)max(cnt, 1);
    out[b * ND + d] = (cnt > 0) ? s / denom : 0.f;
}

extern "C" void kernel_launch(void* const* d_in, const int* in_sizes, int n_in,
                              void* d_out, int out_size, void* d_ws, size_t ws_size,
                              hipStream_t stream) {
    const float* x = (const float*)d_in[0];
    float* out = (float*)d_out;
    float* ws = (float*)d_ws;
    // ws layout (floats): [0..8) scale | [16..16400) sq | [16400..32784) dens | [32784..32792) thr
    float* scale = ws;
    float* sq    = ws + 16;
    float* dens  = ws + 16 + NB * NN;
    float* thr   = ws + 16 + 2 * NB * NN;

    k_stats<<<NB, 256, 0, stream>>>(x, scale);
    k_sq<<<NB * NN / 4, 256, 0, stream>>>(x, sq);
    dim3 gdens(NN / 64, NB);
    k_dens<<<gdens, 256, 0, stream>>>(x, sq, scale, dens);
    k_dstats<<<NB, 256, 0, stream>>>(dens, thr);
    k_mask<<<NB, 256, 0, stream>>>(x, dens, thr, out);
}

// Round 2
// 125.980 us; speedup vs baseline: 9.0659x; 9.0659x over previous
//
#include <hip/hip_runtime.h>
#include <math.h>

#define NB 8
#define NN 2048
#define ND 256

typedef _Float16 f16;
typedef f16 f16x8 __attribute__((ext_vector_type(8)));
typedef float f32x4 __attribute__((ext_vector_type(4)));

static constexpr float EPS = 1e-6f;

__device__ __forceinline__ void gload16(const void* g, void* l) {
    __builtin_amdgcn_global_load_lds(
        (const __attribute__((address_space(1))) unsigned int*)g,
        (__attribute__((address_space(3))) unsigned int*)l, 16, 0, 0);
}

// ---- k_prep: x -> (hi,lo) fp16 split + per-(b,d) partial sum/sumsq --------
__global__ __launch_bounds__(256) void k_prep(const float* __restrict__ x,
                                              f16* __restrict__ xh, f16* __restrict__ xl,
                                              float* __restrict__ partS,
                                              float* __restrict__ partSS) {
    int b = blockIdx.y, ch = blockIdx.x;            // grid (32, 8): 64 rows/block
    int d = threadIdx.x;                            // feature
    size_t base = ((size_t)b * NN + (size_t)ch * 64) * ND;
    float s = 0.f, ss = 0.f;
    for (int r = 0; r < 64; ++r) {
        float v = x[base + r * ND + d];
        s += v; ss += v * v;
        f16 h = (f16)v;
        xh[base + r * ND + d] = h;
        xl[base + r * ND + d] = (f16)(v - (float)h);
    }
    partS[(b * 32 + ch) * ND + d] = s;
    partSS[(b * 32 + ch) * ND + d] = ss;
}

// ---- k_sq: row squared norms ----------------------------------------------
__global__ __launch_bounds__(256) void k_sq(const float* __restrict__ x,
                                            float* __restrict__ sq) {
    int row = blockIdx.x * 4 + (threadIdx.x >> 6);  // one wave per row
    int lane = threadIdx.x & 63;
    const float4* xr = (const float4*)(x + (size_t)row * ND);
    float4 v = xr[lane];
    float s = v.x * v.x + v.y * v.y + v.z * v.z + v.w * v.w;
    #pragma unroll
    for (int off = 32; off > 0; off >>= 1) s += __shfl_down(s, off, 64);
    if (lane == 0) sq[row] = s;
}

// ---- k_scale: sigma -> sc; em[b][n] = exp(-sq*sc) -------------------------
__global__ __launch_bounds__(256) void k_scale(const float* __restrict__ partS,
                                               const float* __restrict__ partSS,
                                               const float* __restrict__ sq,
                                               float* __restrict__ scale,
                                               float* __restrict__ em) {
    int b = blockIdx.x, d = threadIdx.x;
    float s = 0.f, ss = 0.f;
    for (int ch = 0; ch < 32; ++ch) {
        s += partS[(b * 32 + ch) * ND + d];
        ss += partSS[(b * 32 + ch) * ND + d];
    }
    float mean = s * (1.0f / NN);
    float var = ss * (1.0f / NN) - mean * mean;
    float sd = sqrtf(fmaxf(var, 0.f));
    __shared__ float red[256];
    __shared__ float s_sc;
    red[d] = sd;
    __syncthreads();
    for (int off = 128; off > 0; off >>= 1) {
        if (d < off) red[d] += red[d + off];
        __syncthreads();
    }
    if (d == 0) {
        float sigma = red[0] * (1.0f / ND) + EPS;
        double c = pow(4.0 / (ND + 2), 1.0 / (ND + 4)) * pow((double)NN, -1.0 / (ND + 4));
        float h = (float)c * sigma + EPS;
        s_sc = 1.0f / ((float)ND * (2.0f * h * h + EPS));
        scale[b] = s_sc;
    }
    __syncthreads();
    float sc = s_sc;
    for (int n = d; n < NN; n += 256) em[b * NN + n] = __expf(-sq[b * NN + n] * sc);
}

// ---- k_dens: split-fp16 MFMA GEMM (X X^T) fused with exp + col-sum --------
// 128x128 tile, BK=32, 4 waves (2x2), each wave 64x64 via 4x4 16x16 frags.
__global__ __launch_bounds__(256, 3) void k_dens(const f16* __restrict__ xh,
                                                 const f16* __restrict__ xl,
                                                 const float* __restrict__ em,
                                                 const float* __restrict__ scale,
                                                 float* __restrict__ dens_part) {
    int b = blockIdx.z;
    int n0 = blockIdx.x * 128;   // density rows
    int m0 = blockIdx.y * 128;   // summed cols
    int tid = threadIdx.x;
    int w = tid >> 6, lane = tid & 63;
    int wr = w >> 1, wc = w & 1;

    __shared__ alignas(16) f16 sAh[128 * 32];
    __shared__ alignas(16) f16 sAl[128 * 32];
    __shared__ alignas(16) f16 sBh[128 * 32];
    __shared__ alignas(16) f16 sBl[128 * 32];
    __shared__ float dl[2][128];

    const size_t xb = (size_t)b * NN * ND;
    const f16* gAh = xh + xb + (size_t)n0 * ND;
    const f16* gAl = xl + xb + (size_t)n0 * ND;
    const f16* gBh = xh + xb + (size_t)m0 * ND;
    const f16* gBl = xl + xb + (size_t)m0 * ND;

    // per-lane ds_read byte offsets (within a tile): row*64B, chunk XOR-swizzled
    int offA[4], offB[4];
    #pragma unroll
    for (int i = 0; i < 4; ++i) {
        int rA = wr * 64 + i * 16 + (lane & 15);
        offA[i] = rA * 64 + (((lane >> 4) * 16) ^ (((rA >> 1) & 3) << 4));
        int rB = wc * 64 + i * 16 + (lane & 15);
        offB[i] = rB * 64 + (((lane >> 4) * 16) ^ (((rB >> 1) & 3) << 4));
    }

    f32x4 acc[4][4];
    #pragma unroll
    for (int i = 0; i < 4; ++i)
        #pragma unroll
        for (int j = 0; j < 4; ++j)
            acc[i][j] = (f32x4){0.f, 0.f, 0.f, 0.f};

    for (int kt = 0; kt < ND / 32; ++kt) {
        int k0 = kt * 32;
        // stage 4 tiles; linear LDS dest, inverse-swizzled global source
        #pragma unroll
        for (int pass = 0; pass < 2; ++pass) {
            int f = pass * 256 + w * 64 + lane;     // 16B-chunk index 0..511
            int row = f >> 2;
            int c = f & 3;
            int col = ((c ^ ((row >> 1) & 3)) << 3);  // fp16 col (pre-swizzled src)
            size_t go = (size_t)row * ND + k0 + col;
            int lo = pass * 2048 + w * 512;           // f16 units, wave-uniform
            gload16(gAh + go, sAh + lo);
            gload16(gAl + go, sAl + lo);
            gload16(gBh + go, sBh + lo);
            gload16(gBl + go, sBl + lo);
        }
        __syncthreads();

        f16x8 ah[4], al[4], bh[4], bl[4];
        #pragma unroll
        for (int i = 0; i < 4; ++i) {
            ah[i] = *(const f16x8*)((const char*)sAh + offA[i]);
            al[i] = *(const f16x8*)((const char*)sAl + offA[i]);
            bh[i] = *(const f16x8*)((const char*)sBh + offB[i]);
            bl[i] = *(const f16x8*)((const char*)sBl + offB[i]);
        }
        #pragma unroll
        for (int i = 0; i < 4; ++i)
            #pragma unroll
            for (int j = 0; j < 4; ++j) {
                acc[i][j] = __builtin_amdgcn_mfma_f32_16x16x32_f16(ah[i], bh[j], acc[i][j], 0, 0, 0);
                acc[i][j] = __builtin_amdgcn_mfma_f32_16x16x32_f16(ah[i], bl[j], acc[i][j], 0, 0, 0);
                acc[i][j] = __builtin_amdgcn_mfma_f32_16x16x32_f16(al[i], bh[j], acc[i][j], 0, 0, 0);
            }
        __syncthreads();
    }

    // epilogue: dens_partial[row] = sum_cols em[col] * exp(2*sc*dot)
    float sc2 = 2.0f * scale[b];
    float emv[4];
    #pragma unroll
    for (int j = 0; j < 4; ++j)
        emv[j] = em[b * NN + m0 + wc * 64 + j * 16 + (lane & 15)];

    #pragma unroll
    for (int i = 0; i < 4; ++i)
        #pragma unroll
        for (int e = 0; e < 4; ++e) {
            float s = 0.f;
            #pragma unroll
            for (int j = 0; j < 4; ++j)
                s += emv[j] * __expf(sc2 * acc[i][j][e]);
            s += __shfl_xor(s, 1, 64);
            s += __shfl_xor(s, 2, 64);
            s += __shfl_xor(s, 4, 64);
            s += __shfl_xor(s, 8, 64);
            if ((lane & 15) == 0)
                dl[wc][wr * 64 + i * 16 + (lane >> 4) * 4 + e] = s;
        }
    __syncthreads();
    if (tid < 128)
        dens_part[((size_t)(b * 16) + blockIdx.y) * NN + n0 + tid] = dl[0][tid] + dl[1][tid];
}

// ---- k_dfinal: dens = em * sum(partials); mean/std(ddof=1) -> thr ---------
__global__ __launch_bounds__(256) void k_dfinal(const float* __restrict__ part,
                                                const float* __restrict__ em,
                                                float* __restrict__ dens,
                                                float* __restrict__ thr) {
    int b = blockIdx.x, t = threadIdx.x;
    __shared__ float red[256];
    float accs = 0.f;
    for (int n = t; n < NN; n += 256) {
        float s = 0.f;
        for (int mt = 0; mt < 16; ++mt) s += part[((size_t)(b * 16 + mt)) * NN + n];
        s *= em[b * NN + n];
        dens[b * NN + n] = s;
        accs += s;
    }
    red[t] = accs;
    __syncthreads();
    for (int off = 128; off > 0; off >>= 1) {
        if (t < off) red[t] += red[t + off];
        __syncthreads();
    }
    float mean = red[0] * (1.0f / NN);
    __syncthreads();
    float vs = 0.f;
    for (int n = t; n < NN; n += 256) {
        float d2 = dens[b * NN + n] - mean;
        vs += d2 * d2;
    }
    red[t] = vs;
    __syncthreads();
    for (int off = 128; off > 0; off >>= 1) {
        if (t < off) red[t] += red[t + off];
        __syncthreads();
    }
    if (t == 0) thr[b] = mean - 2.0f * sqrtf(red[0] / (float)(NN - 1));
}

// ---- k_maskpart: masked partial feature sums ------------------------------
__global__ __launch_bounds__(256) void k_maskpart(const float* __restrict__ x,
                                                  const float* __restrict__ dens,
                                                  const float* __restrict__ thr,
                                                  float* __restrict__ partM,
                                                  int* __restrict__ partC) {
    int b = blockIdx.y, ch = blockIdx.x;     // grid (16, 8): 128 rows/block
    int d = threadIdx.x;
    float tv = thr[b];
    float s = 0.f;
    int cnt = 0;
    for (int r = 0; r < 128; ++r) {
        int n = ch * 128 + r;
        if (dens[b * NN + n] > tv) {         // block-uniform branch
            s += x[((size_t)b * NN + n) * ND + d];
            ++cnt;
        }
    }
    partM[(b * 16 + ch) * ND + d] = s;
    if (d == 0) partC[b * 16 + ch] = cnt;
}

// ---- k_out: combine --------------------------------------------------------
__global__ __launch_bounds__(256) void k_out(const float* __restrict__ partM,
                                             const int* __restrict__ partC,
                                             float* __restrict__ out) {
    int b = blockIdx.x, d = threadIdx.x;
    float s = 0.f;
    int cnt = 0;
    for (int ch = 0; ch < 16; ++ch) {
        s += partM[(b * 16 + ch) * ND + d];
        cnt += partC[b * 16 + ch];
    }
    out[b * ND + d] = (cnt > 0) ? s / (float)max(cnt, 1) : 0.f;
}

extern "C" void kernel_launch(void* const* d_in, const int* in_sizes, int n_in,
                              void* d_out, int out_size, void* d_ws, size_t ws_size,
                              hipStream_t stream) {
    const float* x = (const float*)d_in[0];
    float* out = (float*)d_out;

    char* p = (char*)d_ws;
    f16* xh = (f16*)p;            p += (size_t)NB * NN * ND * 2;     // 8 MB
    f16* xl = (f16*)p;            p += (size_t)NB * NN * ND * 2;     // 8 MB
    float* sq = (float*)p;        p += (size_t)NB * NN * 4;
    float* em = (float*)p;        p += (size_t)NB * NN * 4;
    float* partS = (float*)p;     p += (size_t)NB * 32 * ND * 4;
    float* partSS = (float*)p;    p += (size_t)NB * 32 * ND * 4;
    float* scale = (float*)p;     p += 256;
    float* dens_part = (float*)p; p += (size_t)NB * 16 * NN * 4;     // 2 MB
    float* dens = (float*)p;      p += (size_t)NB * NN * 4;
    float* thr = (float*)p;       p += 256;
    float* partM = (float*)p;     p += (size_t)NB * 16 * ND * 4;
    int* partC = (int*)p;         p += (size_t)NB * 16 * 4;

    k_prep<<<dim3(32, NB), 256, 0, stream>>>(x, xh, xl, partS, partSS);
    k_sq<<<NB * NN / 4, 256, 0, stream>>>(x, sq);
    k_scale<<<NB, 256, 0, stream>>>(partS, partSS, sq, scale, em);
    k_dens<<<dim3(16, 16, NB), 256, 0, stream>>>(xh, xl, em, scale, dens_part);
    k_dfinal<<<NB, 256, 0, stream>>>(dens_part, em, dens, thr);
    k_maskpart<<<dim3(16, NB), 256, 0, stream>>>(x, dens, thr, partM, partC);
    k_out<<<NB, 256, 0, stream>>>(partM, partC, out);
}

// Round 3
// 88.846 us; speedup vs baseline: 12.8551x; 1.4180x over previous
//
#include <hip/hip_runtime.h>
#include <math.h>

#define NB 8
#define NN 2048
#define ND 256

typedef _Float16 f16;
typedef f16 f16x8 __attribute__((ext_vector_type(8)));
typedef f16 f16x4 __attribute__((ext_vector_type(4)));
typedef float f32x4 __attribute__((ext_vector_type(4)));

static constexpr float EPS = 1e-6f;

__device__ __forceinline__ void gload16(const void* g, void* l) {
    __builtin_amdgcn_global_load_lds(
        (const __attribute__((address_space(1))) unsigned int*)g,
        (__attribute__((address_space(3))) unsigned int*)l, 16, 0, 0);
}

// ---- k_prep: x -> (hi,lo) fp16 split + per-(b,d) partial sum/sumsq --------
// grid (32, NB); thread t: feature chunk c=t&63 (4 feats), rowgroup rg=t>>6.
__global__ __launch_bounds__(256) void k_prep(const float* __restrict__ x,
                                              f16* __restrict__ xh, f16* __restrict__ xl,
                                              float* __restrict__ partS,
                                              float* __restrict__ partSS) {
    int b = blockIdx.y, ch = blockIdx.x;
    int t = threadIdx.x;
    int c = t & 63, rg = t >> 6;
    size_t base = ((size_t)b * NN + (size_t)ch * 64) * ND;
    float s0 = 0.f, s1 = 0.f, s2 = 0.f, s3 = 0.f;
    float q0 = 0.f, q1 = 0.f, q2 = 0.f, q3 = 0.f;
    for (int r = rg; r < 64; r += 4) {
        float4 v = *(const float4*)&x[base + (size_t)r * ND + c * 4];
        s0 += v.x; s1 += v.y; s2 += v.z; s3 += v.w;
        q0 += v.x * v.x; q1 += v.y * v.y; q2 += v.z * v.z; q3 += v.w * v.w;
        f16 h0 = (f16)v.x, h1 = (f16)v.y, h2 = (f16)v.z, h3 = (f16)v.w;
        f16x4 hv = {h0, h1, h2, h3};
        f16x4 lv = {(f16)(v.x - (float)h0), (f16)(v.y - (float)h1),
                    (f16)(v.z - (float)h2), (f16)(v.w - (float)h3)};
        *(f16x4*)&xh[base + (size_t)r * ND + c * 4] = hv;
        *(f16x4*)&xl[base + (size_t)r * ND + c * 4] = lv;
    }
    __shared__ float rS[4][64][4];
    __shared__ float rQ[4][64][4];
    rS[rg][c][0] = s0; rS[rg][c][1] = s1; rS[rg][c][2] = s2; rS[rg][c][3] = s3;
    rQ[rg][c][0] = q0; rQ[rg][c][1] = q1; rQ[rg][c][2] = q2; rQ[rg][c][3] = q3;
    __syncthreads();
    if (rg == 0) {
        #pragma unroll
        for (int e = 0; e < 4; ++e) {
            float S = rS[0][c][e] + rS[1][c][e] + rS[2][c][e] + rS[3][c][e];
            float Q = rQ[0][c][e] + rQ[1][c][e] + rQ[2][c][e] + rQ[3][c][e];
            partS[(b * 32 + ch) * ND + c * 4 + e] = S;
            partSS[(b * 32 + ch) * ND + c * 4 + e] = Q;
        }
    }
}

// ---- k_sq: row squared norms ----------------------------------------------
__global__ __launch_bounds__(256) void k_sq(const float* __restrict__ x,
                                            float* __restrict__ sq) {
    int row = blockIdx.x * 4 + (threadIdx.x >> 6);
    int lane = threadIdx.x & 63;
    const float4* xr = (const float4*)(x + (size_t)row * ND);
    float4 v = xr[lane];
    float s = v.x * v.x + v.y * v.y + v.z * v.z + v.w * v.w;
    #pragma unroll
    for (int off = 32; off > 0; off >>= 1) s += __shfl_down(s, off, 64);
    if (lane == 0) sq[row] = s;
}

// ---- k_scale: sigma -> sc; em[b][n] = exp(-sq*sc) -------------------------
__global__ __launch_bounds__(256) void k_scale(const float* __restrict__ partS,
                                               const float* __restrict__ partSS,
                                               const float* __restrict__ sq,
                                               float* __restrict__ scale,
                                               float* __restrict__ em) {
    int b = blockIdx.x, d = threadIdx.x;
    float s = 0.f, ss = 0.f;
    for (int ch = 0; ch < 32; ++ch) {
        s += partS[(b * 32 + ch) * ND + d];
        ss += partSS[(b * 32 + ch) * ND + d];
    }
    float mean = s * (1.0f / NN);
    float var = ss * (1.0f / NN) - mean * mean;
    float sd = sqrtf(fmaxf(var, 0.f));
    __shared__ float red[256];
    __shared__ float s_sc;
    red[d] = sd;
    __syncthreads();
    for (int off = 128; off > 0; off >>= 1) {
        if (d < off) red[d] += red[d + off];
        __syncthreads();
    }
    if (d == 0) {
        float sigma = red[0] * (1.0f / ND) + EPS;
        double c = pow(4.0 / (ND + 2), 1.0 / (ND + 4)) * pow((double)NN, -1.0 / (ND + 4));
        float h = (float)c * sigma + EPS;
        s_sc = 1.0f / ((float)ND * (2.0f * h * h + EPS));
        scale[b] = s_sc;
    }
    __syncthreads();
    float sc = s_sc;
    for (int n = d; n < NN; n += 256) em[b * NN + n] = __expf(-sq[b * NN + n] * sc);
}

// ---- k_dens: symmetric split-fp16 MFMA GEMM fused with exp + dual sums ----
// Only upper-triangular 128x128 tile pairs (i<=j). Off-diagonal blocks emit
// row-weighted sums (tile i rows) AND col-weighted sums (tile j rows).
__global__ __launch_bounds__(256, 3) void k_dens(const f16* __restrict__ xh,
                                                 const f16* __restrict__ xl,
                                                 const float* __restrict__ em,
                                                 const float* __restrict__ scale,
                                                 float* __restrict__ dens_part) {
    int b = blockIdx.y;
    // decode triangular index -> (ti, tj) with ti <= tj
    int t = blockIdx.x;
    int ti = 0, basec = 0;
    while (t >= basec + (16 - ti)) { basec += 16 - ti; ++ti; }
    int tj = ti + (t - basec);
    int n0 = ti * 128;   // A rows (density rows for row-part)
    int m0 = tj * 128;   // B rows (density rows for col-part)

    int tid = threadIdx.x;
    int w = tid >> 6, lane = tid & 63;
    int wr = w >> 1, wc = w & 1;

    __shared__ alignas(16) f16 sAh[128 * 32];
    __shared__ alignas(16) f16 sAl[128 * 32];
    __shared__ alignas(16) f16 sBh[128 * 32];
    __shared__ alignas(16) f16 sBl[128 * 32];
    __shared__ float dl[2][128];
    __shared__ float dc[2][128];

    const size_t xb = (size_t)b * NN * ND;
    const f16* gAh = xh + xb + (size_t)n0 * ND;
    const f16* gAl = xl + xb + (size_t)n0 * ND;
    const f16* gBh = xh + xb + (size_t)m0 * ND;
    const f16* gBl = xl + xb + (size_t)m0 * ND;

    int offA[4], offB[4];
    #pragma unroll
    for (int i = 0; i < 4; ++i) {
        int rA = wr * 64 + i * 16 + (lane & 15);
        offA[i] = rA * 64 + (((lane >> 4) * 16) ^ (((rA >> 1) & 3) << 4));
        int rB = wc * 64 + i * 16 + (lane & 15);
        offB[i] = rB * 64 + (((lane >> 4) * 16) ^ (((rB >> 1) & 3) << 4));
    }

    f32x4 acc[4][4];
    #pragma unroll
    for (int i = 0; i < 4; ++i)
        #pragma unroll
        for (int j = 0; j < 4; ++j)
            acc[i][j] = (f32x4){0.f, 0.f, 0.f, 0.f};

    for (int kt = 0; kt < ND / 32; ++kt) {
        int k0 = kt * 32;
        #pragma unroll
        for (int pass = 0; pass < 2; ++pass) {
            int f = pass * 256 + w * 64 + lane;
            int row = f >> 2;
            int c = f & 3;
            int col = ((c ^ ((row >> 1) & 3)) << 3);
            size_t go = (size_t)row * ND + k0 + col;
            int lo = pass * 2048 + w * 512;
            gload16(gAh + go, sAh + lo);
            gload16(gAl + go, sAl + lo);
            gload16(gBh + go, sBh + lo);
            gload16(gBl + go, sBl + lo);
        }
        __syncthreads();

        f16x8 ah[4], al[4], bh[4], bl[4];
        #pragma unroll
        for (int i = 0; i < 4; ++i) {
            ah[i] = *(const f16x8*)((const char*)sAh + offA[i]);
            al[i] = *(const f16x8*)((const char*)sAl + offA[i]);
            bh[i] = *(const f16x8*)((const char*)sBh + offB[i]);
            bl[i] = *(const f16x8*)((const char*)sBl + offB[i]);
        }
        #pragma unroll
        for (int i = 0; i < 4; ++i)
            #pragma unroll
            for (int j = 0; j < 4; ++j) {
                acc[i][j] = __builtin_amdgcn_mfma_f32_16x16x32_f16(ah[i], bh[j], acc[i][j], 0, 0, 0);
                acc[i][j] = __builtin_amdgcn_mfma_f32_16x16x32_f16(ah[i], bl[j], acc[i][j], 0, 0, 0);
                acc[i][j] = __builtin_amdgcn_mfma_f32_16x16x32_f16(al[i], bh[j], acc[i][j], 0, 0, 0);
            }
        __syncthreads();
    }

    // epilogue: K = exp(2sc*dot); row-part += em[col]*K ; col-part += em[row]*K
    float sc2 = 2.0f * scale[b];
    float emv[4];
    #pragma unroll
    for (int j = 0; j < 4; ++j)
        emv[j] = em[b * NN + m0 + wc * 64 + j * 16 + (lane & 15)];
    float emn[4][4];
    #pragma unroll
    for (int i = 0; i < 4; ++i) {
        float4 v = *(const float4*)&em[b * NN + n0 + wr * 64 + i * 16 + (lane >> 4) * 4];
        emn[i][0] = v.x; emn[i][1] = v.y; emn[i][2] = v.z; emn[i][3] = v.w;
    }

    float colsum[4] = {0.f, 0.f, 0.f, 0.f};
    #pragma unroll
    for (int i = 0; i < 4; ++i)
        #pragma unroll
        for (int e = 0; e < 4; ++e) {
            float rs = 0.f;
            #pragma unroll
            for (int j = 0; j < 4; ++j) {
                float v = __expf(sc2 * acc[i][j][e]);
                rs += emv[j] * v;
                colsum[j] += emn[i][e] * v;
            }
            rs += __shfl_xor(rs, 1, 64);
            rs += __shfl_xor(rs, 2, 64);
            rs += __shfl_xor(rs, 4, 64);
            rs += __shfl_xor(rs, 8, 64);
            if ((lane & 15) == 0)
                dl[wc][wr * 64 + i * 16 + (lane >> 4) * 4 + e] = rs;
        }
    #pragma unroll
    for (int j = 0; j < 4; ++j) {
        float cs = colsum[j];
        cs += __shfl_xor(cs, 16, 64);
        cs += __shfl_xor(cs, 32, 64);
        if ((lane >> 4) == 0)
            dc[wr][wc * 64 + j * 16 + (lane & 15)] = cs;
    }
    __syncthreads();
    if (tid < 128) {
        dens_part[((size_t)(b * 16) + tj) * NN + n0 + tid] = dl[0][tid] + dl[1][tid];
    } else if (ti != tj) {
        int c = tid - 128;
        dens_part[((size_t)(b * 16) + ti) * NN + m0 + c] = dc[0][c] + dc[1][c];
    }
}

// ---- k_dsum: dens = em * sum(16 partials); grid (8, NB) -------------------
__global__ __launch_bounds__(256) void k_dsum(const float* __restrict__ part,
                                              const float* __restrict__ em,
                                              float* __restrict__ dens) {
    int b = blockIdx.y;
    int n = blockIdx.x * 256 + threadIdx.x;
    float s = 0.f;
    #pragma unroll
    for (int mt = 0; mt < 16; ++mt) s += part[((size_t)(b * 16 + mt)) * NN + n];
    dens[b * NN + n] = s * em[b * NN + n];
}

// ---- k_dstats: per-batch density mean/std(ddof=1) -> thr ------------------
__global__ __launch_bounds__(256) void k_dstats(const float* __restrict__ dens,
                                                float* __restrict__ thr) {
    int b = blockIdx.x, t = threadIdx.x;
    const float* db = dens + b * NN;
    __shared__ float red[256];
    float s = 0.f;
    for (int n = t; n < NN; n += 256) s += db[n];
    red[t] = s;
    __syncthreads();
    for (int off = 128; off > 0; off >>= 1) {
        if (t < off) red[t] += red[t + off];
        __syncthreads();
    }
    float mean = red[0] * (1.0f / NN);
    __syncthreads();
    float vs = 0.f;
    for (int n = t; n < NN; n += 256) {
        float d2 = db[n] - mean;
        vs += d2 * d2;
    }
    red[t] = vs;
    __syncthreads();
    for (int off = 128; off > 0; off >>= 1) {
        if (t < off) red[t] += red[t + off];
        __syncthreads();
    }
    if (t == 0) thr[b] = mean - 2.0f * sqrtf(red[0] / (float)(NN - 1));
}

// ---- k_maskpart: masked partial feature sums (vectorized) -----------------
// grid (16, NB): 128 rows/block; thread: chunk c=t&63 (4 feats), rg=t>>6.
__global__ __launch_bounds__(256) void k_maskpart(const float* __restrict__ x,
                                                  const float* __restrict__ dens,
                                                  const float* __restrict__ thr,
                                                  float* __restrict__ partM,
                                                  int* __restrict__ partC) {
    int b = blockIdx.y, ch = blockIdx.x;
    int t = threadIdx.x;
    int c = t & 63, rg = t >> 6;
    float tv = thr[b];
    float s0 = 0.f, s1 = 0.f, s2 = 0.f, s3 = 0.f;
    int cnt = 0;
    for (int r = rg; r < 128; r += 4) {
        int n = ch * 128 + r;
        if (dens[b * NN + n] > tv) {     // wave-uniform (one rowgroup per wave)
            float4 v = *(const float4*)&x[((size_t)b * NN + n) * ND + c * 4];
            s0 += v.x; s1 += v.y; s2 += v.z; s3 += v.w;
            ++cnt;
        }
    }
    __shared__ float rS[4][64][4];
    __shared__ int rC[4];
    rS[rg][c][0] = s0; rS[rg][c][1] = s1; rS[rg][c][2] = s2; rS[rg][c][3] = s3;
    if (c == 0) rC[rg] = cnt;
    __syncthreads();
    if (rg == 0) {
        #pragma unroll
        for (int e = 0; e < 4; ++e) {
            float S = rS[0][c][e] + rS[1][c][e] + rS[2][c][e] + rS[3][c][e];
            partM[(b * 16 + ch) * ND + c * 4 + e] = S;
        }
        if (c == 0) partC[b * 16 + ch] = rC[0] + rC[1] + rC[2] + rC[3];
    }
}

// ---- k_out: combine --------------------------------------------------------
__global__ __launch_bounds__(256) void k_out(const float* __restrict__ partM,
                                             const int* __restrict__ partC,
                                             float* __restrict__ out) {
    int b = blockIdx.x, d = threadIdx.x;
    float s = 0.f;
    int cnt = 0;
    for (int ch = 0; ch < 16; ++ch) {
        s += partM[(b * 16 + ch) * ND + d];
        cnt += partC[b * 16 + ch];
    }
    out[b * ND + d] = (cnt > 0) ? s / (float)max(cnt, 1) : 0.f;
}

extern "C" void kernel_launch(void* const* d_in, const int* in_sizes, int n_in,
                              void* d_out, int out_size, void* d_ws, size_t ws_size,
                              hipStream_t stream) {
    const float* x = (const float*)d_in[0];
    float* out = (float*)d_out;

    char* p = (char*)d_ws;
    f16* xh = (f16*)p;            p += (size_t)NB * NN * ND * 2;
    f16* xl = (f16*)p;            p += (size_t)NB * NN * ND * 2;
    float* sq = (float*)p;        p += (size_t)NB * NN * 4;
    float* em = (float*)p;        p += (size_t)NB * NN * 4;
    float* partS = (float*)p;     p += (size_t)NB * 32 * ND * 4;
    float* partSS = (float*)p;    p += (size_t)NB * 32 * ND * 4;
    float* scale = (float*)p;     p += 256;
    float* dens_part = (float*)p; p += (size_t)NB * 16 * NN * 4;
    float* dens = (float*)p;      p += (size_t)NB * NN * 4;
    float* thr = (float*)p;       p += 256;
    float* partM = (float*)p;     p += (size_t)NB * 16 * ND * 4;
    int* partC = (int*)p;         p += (size_t)NB * 16 * 4;

    k_prep<<<dim3(32, NB), 256, 0, stream>>>(x, xh, xl, partS, partSS);
    k_sq<<<NB * NN / 4, 256, 0, stream>>>(x, sq);
    k_scale<<<NB, 256, 0, stream>>>(partS, partSS, sq, scale, em);
    k_dens<<<dim3(136, NB), 256, 0, stream>>>(xh, xl, em, scale, dens_part);
    k_dsum<<<dim3(8, NB), 256, 0, stream>>>(dens_part, em, dens);
    k_dstats<<<NB, 256, 0, stream>>>(dens, thr);
    k_maskpart<<<dim3(16, NB), 256, 0, stream>>>(x, dens, thr, partM, partC);
    k_out<<<NB, 256, 0, stream>>>(partM, partC, out);
}